// Round 2
// baseline (1353.237 us; speedup 1.0000x reference)
//
#include <hip/hip_runtime.h>

#define N_ITER 20
#define ALPHA 0.01f

typedef unsigned short ushort_t;
typedef __attribute__((ext_vector_type(8))) short bf16x8;
typedef __attribute__((ext_vector_type(16))) float f32x16;

__device__ __forceinline__ float csign(int a, int b) {
    int s = 0;
    for (int aa = a >> 1; aa; aa >>= 1) s += __popc(aa & b);
    return (s & 1) ? -1.0f : 1.0f;
}

__device__ __forceinline__ float revsign(int b) {
    int k = __popc(b);
    return ((k * (k - 1) / 2) & 1) ? -1.0f : 1.0f;
}

__device__ __forceinline__ ushort_t f2bf(float f) {
    union { float f; unsigned u; } v;
    v.f = f;
    unsigned r = v.u + 0x7fffu + ((v.u >> 16) & 1u);  // RNE; inputs finite
    return (ushort_t)(r >> 16);
}

// Swizzled storage for logical (r, k) in an [R][K] bf16 A-side operand buffer.
// Within each 64-elem k-group (128 B), 16B block j lives at j ^ (r&7).
// Verbatim LDS staging; fragment ds_read_b128 conflict-free (verified earlier).
__device__ __forceinline__ size_t swz64(int r, int k, int K) {
    return (size_t)r * K + (k & ~63) + ((((k >> 3) ^ r) & 7) << 3) + (k & 7);
}

// B-side fragment-record layout ("bfrag"): weights are consumed in a fixed
// pattern, so store them pre-arranged. 1KB record per (k-chunk, col-group
// cg=r>>5, s); record[lane*8 ushorts] = the 8 bf16 the MFMA B-fragment wants:
// lane = lh*32 + (r&31), covering k' = 16s + 8*lh + 0..7 within the chunk.
// One coalesced global_load_dwordx4 per fragment, L2 -> VGPR, no LDS at all.
__device__ __forceinline__ size_t bfrag(int r, int k, int NR) {
    return ((((size_t)(k >> 6) * (NR >> 5) + (r >> 5)) * 4 + ((k >> 4) & 3)) * 512)
           + (size_t)(((((k >> 3) & 1) * 32) + (r & 31)) * 8 + (k & 7));
}

__device__ __forceinline__ void async16(const void* g, void* l) {
    __builtin_amdgcn_global_load_lds((const __attribute__((address_space(1))) void*)g,
                                     (__attribute__((address_space(3))) void*)l, 16, 0, 0);
}

// Build bf16 GP matrices from W [P, Q, 8]:
//  MfA    swz64 [Q8][P8]: forward GP, A-layout    MfA[q8+a][p8+c]    = s*w
//  Mrbt   bfrag NR=Q8, K=P8: reverse GP, B^T      (r=q8+c, k=p8+a)   = s*rev*w
//  Mrneg  bfrag: -Mrbt
//  Mbtneg bfrag NR=P8, K=Q8: -forward GP, B^T     (r=p8+c, k=q8+a)   = -s*w
__global__ void build_M_kernel(const float* __restrict__ W, ushort_t* __restrict__ MfA,
                               ushort_t* __restrict__ Mrbt, ushort_t* __restrict__ Mrneg,
                               ushort_t* __restrict__ Mbtneg, int P, int Q) {
    int idx = blockIdx.x * blockDim.x + threadIdx.x;
    int total = P * Q * 64;
    if (idx >= total) return;
    int c = idx & 7;
    int a = (idx >> 3) & 7;
    int pq = idx >> 6;
    int q = pq % Q;
    int p = pq / Q;
    int b = a ^ c;
    float w = W[((size_t)p * Q + q) * 8 + b];
    float fw = csign(a, b) * w;
    float rw = csign(a, b) * revsign(b) * w;
    MfA[swz64(q * 8 + a, p * 8 + c, P * 8)] = f2bf(fw);
    Mrbt[bfrag(q * 8 + c, p * 8 + a, Q * 8)] = f2bf(rw);
    if (Mrneg) Mrneg[bfrag(q * 8 + c, p * 8 + a, Q * 8)] = f2bf(-rw);
    if (Mbtneg) Mbtneg[bfrag(p * 8 + c, q * 8 + a, P * 8)] = f2bf(-fw);
}

// fp32 [R][K] plain -> bf16 swz64 (A-side)
__global__ void f2bf_swz_kernel(const float* __restrict__ in, ushort_t* __restrict__ out,
                                int n, int kshift) {
    int i = blockIdx.x * blockDim.x + threadIdx.x;
    if (i >= n) return;
    int K = 1 << kshift;
    int r = i >> kshift;
    int k = i & (K - 1);
    out[swz64(r, k, K)] = f2bf(in[i]);
}

// MFMA bf16 GEMM. BM=64 x BN=128 block, BK=64, 256 threads (4 waves 2x2),
// wave tile 32x64 (FI=1, FJ=2 of 32x32x16 MFMAs).
// A-side: LDS-staged (double-buffered, global_load_lds, swz64).
// B-side: bfrag records, global->VGPR coalesced loads, 1-chunk-ahead prefetch
//         into a second register set (pair-unrolled loop => static indexing).
// Two accumulation phases (K then K2) unified into one chunk sequence.
// MODE 1: Fout fp32 = acc                                       (R precompute)
// MODE 2: g=clip(acc - Rf); hn=Xf - a*g; Hout=hn fp32; Bout=swz64(hn)   (H1 update)
// MODE 3: g=clip(acc);      hn=Xf - a*g; Hout=hn fp32; Bout=swz64(hn)   (H2 update)
// MODE 4: Bout[bfrag(col,row,N)] = bf16(acc + (ADDI && row==col))       (G build)
template <int MODE, int BM, int BN, bool ADDI>
__global__ __launch_bounds__(256) void gemm_k(const ushort_t* __restrict__ A,
                                              const ushort_t* __restrict__ BT, int K,
                                              const ushort_t* __restrict__ A2,
                                              const ushort_t* __restrict__ BT2, int K2,
                                              const float* __restrict__ Xf,
                                              const float* __restrict__ Rf,
                                              float* __restrict__ Hout,
                                              ushort_t* __restrict__ Bout,
                                              float* __restrict__ Fout, int N) {
    constexpr int FI = BM / 64;          // 32-row tiles per wave (wave covers BM/2 rows)
    constexpr int FJ = BN / 64;          // 32-col tiles per wave
    constexpr int CPW = BM / 32;         // 1KB A-staging chunks per wave
    constexpr int SZ = BM * 64;          // one LDS A-buffer (ushorts)

    __shared__ ushort_t S[2 * SZ];

    const int t = threadIdx.x;
    const int lane = t & 63;
    const int w = t >> 6;
    const int wr = w >> 1;
    const int wc = w & 1;
    const int l31 = lane & 31;
    const int lh = lane >> 5;
    const int row0 = blockIdx.y * BM;
    const int col0 = blockIdx.x * BN;
    const int srow = lane >> 3;
    const int sk = (lane & 7) * 8;
    const int sw7 = l31 & 7;
    const int cg0 = (col0 >> 5) + wc * FJ;

    f32x16 acc[FI][FJ];
#pragma unroll
    for (int i = 0; i < FI; ++i)
#pragma unroll
        for (int j = 0; j < FJ; ++j)
#pragma unroll
            for (int r = 0; r < 16; ++r) acc[i][j][r] = 0.0f;

    // A-staging global base pointers (per 8-row group owned by this thread)
    const ushort_t* gA1[CPW];
    const ushort_t* gA2[CPW];
    int lofs[CPW];
#pragma unroll
    for (int cc = 0; cc < CPW; ++cc) {
        int ch = cc * 4 + w;
        lofs[cc] = ch * 512;
        gA1[cc] = A + (size_t)(row0 + ch * 8 + srow) * K + sk;
        gA2[cc] = A2 ? (A2 + (size_t)(row0 + ch * 8 + srow) * K2 + sk) : A;
    }

    const int T1 = K >> 6;
    const int T2 = K2 >> 6;
    const int Ttot = T1 + T2;            // always even for our shapes
    const size_t bstride = (size_t)N * 64;  // ushorts per k-chunk of B-records
    const size_t rec0 = ((size_t)cg0 * 4) * 512 + (size_t)lane * 8;

    auto stage = [&](int tt, ushort_t* Sb) {
        if (tt < T1) {
#pragma unroll
            for (int cc = 0; cc < CPW; ++cc)
                async16(gA1[cc] + (size_t)tt * 64, &Sb[lofs[cc]]);
        } else {
            const int tl = tt - T1;
#pragma unroll
            for (int cc = 0; cc < CPW; ++cc)
                async16(gA2[cc] + (size_t)tl * 64, &Sb[lofs[cc]]);
        }
    };

    auto loadB = [&](int tt, bf16x8 (&bq)[4][FJ]) {
        const ushort_t* base;
        if (tt < T1) base = BT + (size_t)tt * bstride + rec0;
        else         base = BT2 + (size_t)(tt - T1) * bstride + rec0;
#pragma unroll
        for (int j = 0; j < FJ; ++j)
#pragma unroll
            for (int s = 0; s < 4; ++s)
                bq[s][j] = *(const bf16x8*)(base + (size_t)(j * 4 + s) * 512);
    };

    auto compute = [&](const ushort_t* Sc, bf16x8 (&bq)[4][FJ]) {
#pragma unroll
        for (int s = 0; s < 4; ++s) {
            int pos = ((2 * s + lh) ^ sw7) * 8;
#pragma unroll
            for (int i = 0; i < FI; ++i) {
                bf16x8 a = *(const bf16x8*)&Sc[(wr * (BM / 2) + i * 32 + l31) * 64 + pos];
#pragma unroll
                for (int j = 0; j < FJ; ++j)
                    acc[i][j] = __builtin_amdgcn_mfma_f32_32x32x16_bf16(a, bq[s][j],
                                                                        acc[i][j], 0, 0, 0);
            }
        }
    };

    bf16x8 b0[4][FJ], b1[4][FJ];

    // prologue: chunk 0 in flight
    stage(0, S);
    loadB(0, b0);
    __syncthreads();  // vmcnt(0) drain — chunk 0 resident

    for (int tt = 0; tt < Ttot; tt += 2) {
        // chunk tt: prefetch tt+1 (always valid; Ttot even), compute from S0/b0
        stage(tt + 1, S + SZ);
        loadB(tt + 1, b1);
        compute(S, b0);
        __syncthreads();
        // chunk tt+1: prefetch tt+2, compute from S1/b1
        if (tt + 2 < Ttot) {
            stage(tt + 2, S);
            loadB(tt + 2, b0);
        }
        compute(S + SZ, b1);
        __syncthreads();
    }

    // epilogue: C/D layout col=lane&31, row=(reg&3)+8*(reg>>2)+4*(lane>>5)
#pragma unroll
    for (int i = 0; i < FI; ++i) {
#pragma unroll
        for (int j = 0; j < FJ; ++j) {
#pragma unroll
            for (int r = 0; r < 16; ++r) {
                int row = row0 + wr * (BM / 2) + i * 32 + (r & 3) + 8 * (r >> 2) + 4 * lh;
                int col = col0 + wc * (BN / 2) + j * 32 + l31;
                size_t off = (size_t)row * N + col;
                float v = acc[i][j][r];
                if (MODE == 1) {
                    Fout[off] = v;
                } else if (MODE == 2) {
                    float h = Xf[off];
                    float g = fminf(fmaxf(v - Rf[off], -1.0f), 1.0f);
                    float hn = h - ALPHA * g;
                    Hout[off] = hn;
                    Bout[swz64(row, col, N)] = f2bf(hn);
                } else if (MODE == 3) {
                    float h = Xf[off];
                    float g = fminf(fmaxf(v, -1.0f), 1.0f);
                    float hn = h - ALPHA * g;
                    Hout[off] = hn;
                    Bout[swz64(row, col, N)] = f2bf(hn);
                } else {  // MODE 4 (square M==N): result is the NEXT GEMM's B-operand
                    float vv = v + ((ADDI && row == col) ? 1.0f : 0.0f);
                    Bout[bfrag(col, row, N)] = f2bf(vv);
                }
            }
        }
    }
}

extern "C" void kernel_launch(void* const* d_in, const int* in_sizes, int n_in,
                              void* d_out, int out_size, void* d_ws, size_t ws_size,
                              hipStream_t stream) {
    const float* X  = (const float*)d_in[0];  // [4096, 256, 8]
    const float* W1 = (const float*)d_in[1];  // [256, 128, 8]
    const float* W2 = (const float*)d_in[2];  // [128, 64, 8]
    const float* h1 = (const float*)d_in[3];  // [4096, 128, 8]
    const float* h2 = (const float*)d_in[4];  // [4096, 64, 8]
    float* out = (float*)d_out;

    const size_t szX  = (size_t)4096 * 2048;
    const size_t szH1 = (size_t)4096 * 1024;
    const size_t szH2 = (size_t)4096 * 512;

    float* outX = out;
    float* H1 = out + szX;
    float* H2 = H1 + szH1;

    // workspace (~77 MB of ~268 MB)
    ushort_t* M1fwdA  = (ushort_t*)d_ws;                 // [1024][2048] swz64
    ushort_t* M1rbt   = M1fwdA + (size_t)1024 * 2048;    // bfrag NR=1024 K=2048
    ushort_t* M2fwdA  = M1rbt + (size_t)1024 * 2048;     // [512][1024] swz64
    ushort_t* M2rbt   = M2fwdA + (size_t)512 * 1024;     // bfrag NR=512 K=1024
    ushort_t* M2rneg  = M2rbt + (size_t)512 * 1024;      // bfrag NR=512 K=1024
    ushort_t* M2btneg = M2rneg + (size_t)512 * 1024;     // bfrag NR=1024 K=512
    ushort_t* GmT1p   = M2btneg + (size_t)1024 * 512;    // bfrag NR=1024 K=1024
    ushort_t* GmT2    = GmT1p + (size_t)1024 * 1024;     // bfrag NR=512 K=512
    ushort_t* Xb      = GmT2 + (size_t)512 * 512;        // [4096][2048] swz64
    ushort_t* H1bA    = Xb + szX;                        // [4096][1024] swz64
    ushort_t* H1bB    = H1bA + szH1;
    ushort_t* H2bA    = H1bB + szH1;                     // [4096][512] swz64
    ushort_t* H2bB    = H2bA + szH2;
    float*    R       = (float*)(H2bB + szH2);           // [4096][1024] fp32

    build_M_kernel<<<(256 * 128 * 64 + 255) / 256, 256, 0, stream>>>(
        W1, M1fwdA, M1rbt, nullptr, nullptr, 256, 128);
    build_M_kernel<<<(128 * 64 * 64 + 255) / 256, 256, 0, stream>>>(
        W2, M2fwdA, M2rbt, M2rneg, M2btneg, 128, 64);

    hipMemcpyAsync(H1, h1, szH1 * sizeof(float), hipMemcpyDeviceToDevice, stream);
    hipMemcpyAsync(H2, h2, szH2 * sizeof(float), hipMemcpyDeviceToDevice, stream);
    f2bf_swz_kernel<<<(int)((szX + 255) / 256), 256, 0, stream>>>(X, Xb, (int)szX, 11);
    f2bf_swz_kernel<<<(int)((szH1 + 255) / 256), 256, 0, stream>>>(h1, H1bA, (int)szH1, 10);
    f2bf_swz_kernel<<<(int)((szH2 + 255) / 256), 256, 0, stream>>>(h2, H2bA, (int)szH2, 9);

    // Precompute R = X@M1r (fp32), GmT1p = (M1@M1r + I)^T, GmT2 = (M2@M2r)^T
    gemm_k<1, 64, 128, false><<<dim3(8, 64), 256, 0, stream>>>(
        Xb, M1rbt, 2048, nullptr, nullptr, 0, nullptr, nullptr, nullptr, nullptr, R, 1024);
    gemm_k<4, 64, 128, true><<<dim3(8, 16), 256, 0, stream>>>(
        M1fwdA, M1rbt, 2048, nullptr, nullptr, 0, nullptr, nullptr, nullptr, GmT1p, nullptr, 1024);
    gemm_k<4, 64, 128, false><<<dim3(4, 8), 256, 0, stream>>>(
        M2fwdA, M2rbt, 1024, nullptr, nullptr, 0, nullptr, nullptr, nullptr, GmT2, nullptr, 512);

    ushort_t* H1old = H1bA; ushort_t* H1new = H1bB;
    ushort_t* H2old = H2bA; ushort_t* H2new = H2bB;
    for (int it = 0; it < N_ITER; ++it) {
        // A: H1 <- H1 - a*clip(H1@Gm1p - H2@M2 - R)   [4096x1024], K=1024+512
        gemm_k<2, 64, 128, false><<<dim3(8, 64), 256, 0, stream>>>(
            H1old, GmT1p, 1024, H2old, M2btneg, 512, H1, R, H1, H1new, nullptr, 1024);
        // B: H2 <- H2 - a*clip(H2@Gm2 - H1new@M2r)    [4096x512],  K=512+1024
        gemm_k<3, 64, 128, false><<<dim3(4, 64), 256, 0, stream>>>(
            H2old, GmT2, 512, H1new, M2rneg, 1024, H2, nullptr, H2, H2new, nullptr, 512);
        ushort_t* tmp;
        tmp = H1old; H1old = H1new; H1new = tmp;
        tmp = H2old; H2old = H2new; H2new = tmp;
    }

    // x passes through unchanged
    hipMemcpyAsync(outX, X, szX * sizeof(float), hipMemcpyDeviceToDevice, stream);
}

// Round 3
// 1225.489 us; speedup vs baseline: 1.1042x; 1.1042x over previous
//
#include <hip/hip_runtime.h>

#define N_ITER 20
#define ALPHA 0.01f

typedef unsigned short ushort_t;
typedef __attribute__((ext_vector_type(8))) short bf16x8;
typedef __attribute__((ext_vector_type(16))) float f32x16;

__device__ __forceinline__ float csign(int a, int b) {
    int s = 0;
    for (int aa = a >> 1; aa; aa >>= 1) s += __popc(aa & b);
    return (s & 1) ? -1.0f : 1.0f;
}

__device__ __forceinline__ float revsign(int b) {
    int k = __popc(b);
    return ((k * (k - 1) / 2) & 1) ? -1.0f : 1.0f;
}

__device__ __forceinline__ ushort_t f2bf(float f) {
    union { float f; unsigned u; } v;
    v.f = f;
    unsigned r = v.u + 0x7fffu + ((v.u >> 16) & 1u);  // RNE; inputs finite
    return (ushort_t)(r >> 16);
}

// Swizzled storage for logical (r, k) in an [R][K] bf16 operand buffer.
// Within each 64-elem k-group (128 B), 16B block j lives at j ^ (r&7).
// Verbatim LDS staging; fragment ds_read_b128 conflict-free (verified earlier).
__device__ __forceinline__ size_t swz64(int r, int k, int K) {
    return (size_t)r * K + (k & ~63) + ((((k >> 3) ^ r) & 7) << 3) + (k & 7);
}

__device__ __forceinline__ void async16(const void* g, void* l) {
    __builtin_amdgcn_global_load_lds((const __attribute__((address_space(1))) void*)g,
                                     (__attribute__((address_space(3))) void*)l, 16, 0, 0);
}

// Build bf16 swz64 GP matrices from W [P, Q, 8]:
//  MfA    [Q8][P8]: forward GP, A-layout    MfA[q8+a][p8+c]    = s*w
//  Mrbt   [Q8][P8]: reverse GP, B^T layout  Mrbt[q8+c][p8+a]   = s*rev*w
//  Mrneg  [Q8][P8]: -Mrbt
//  Mbtneg [P8][Q8]: -forward GP, B^T layout Mbtneg[p8+c][q8+a] = -s*w
__global__ void build_M_kernel(const float* __restrict__ W, ushort_t* __restrict__ MfA,
                               ushort_t* __restrict__ Mrbt, ushort_t* __restrict__ Mrneg,
                               ushort_t* __restrict__ Mbtneg, int P, int Q) {
    int idx = blockIdx.x * blockDim.x + threadIdx.x;
    int total = P * Q * 64;
    if (idx >= total) return;
    int c = idx & 7;
    int a = (idx >> 3) & 7;
    int pq = idx >> 6;
    int q = pq % Q;
    int p = pq / Q;
    int b = a ^ c;
    float w = W[((size_t)p * Q + q) * 8 + b];
    float fw = csign(a, b) * w;
    float rw = csign(a, b) * revsign(b) * w;
    MfA[swz64(q * 8 + a, p * 8 + c, P * 8)] = f2bf(fw);
    Mrbt[swz64(q * 8 + c, p * 8 + a, P * 8)] = f2bf(rw);
    if (Mrneg) Mrneg[swz64(q * 8 + c, p * 8 + a, P * 8)] = f2bf(-rw);
    if (Mbtneg) Mbtneg[swz64(p * 8 + c, q * 8 + a, Q * 8)] = f2bf(-fw);
}

// fp32 [R][K] plain -> bf16 swz64
__global__ void f2bf_swz_kernel(const float* __restrict__ in, ushort_t* __restrict__ out,
                                int n, int kshift) {
    int i = blockIdx.x * blockDim.x + threadIdx.x;
    if (i >= n) return;
    int K = 1 << kshift;
    int r = i >> kshift;
    int k = i & (K - 1);
    out[swz64(r, k, K)] = f2bf(in[i]);
}

// MFMA bf16 GEMM. BM=128 x BN=128 block, BK=64, 256 threads (4 waves 2x2),
// wave tile 64x64 (FI=FJ=2 of 32x32x16 MFMAs, LDS-read:MFMA cycle ratio ~1:1).
// TRIPLE-buffered LDS, 2-chunk-ahead prefetch via global_load_lds, counted
// s_waitcnt vmcnt(CPW) (never drained to 0 in the loop), one raw s_barrier
// per chunk. Two accumulation phases (K then K2) unified into one sequence.
// MODE 1: Fout fp32 = acc                                       (R precompute)
// MODE 2: g=clip(acc - Rf); hn=Xf - a*g; Hout=hn fp32; Bout=swz64(hn)   (H1 update)
// MODE 3: g=clip(acc);      hn=Xf - a*g; Hout=hn fp32; Bout=swz64(hn)   (H2 update)
// MODE 4: Bout[swz64(col,row,N)] = bf16(acc + (ADDI && row==col))       (GmT build)
template <int MODE, int BM, int BN, bool ADDI>
__global__ __launch_bounds__(256) void gemm_k(const ushort_t* __restrict__ A,
                                              const ushort_t* __restrict__ BT, int K,
                                              const ushort_t* __restrict__ A2,
                                              const ushort_t* __restrict__ BT2, int K2,
                                              const float* __restrict__ Xf,
                                              const float* __restrict__ Rf,
                                              float* __restrict__ Hout,
                                              ushort_t* __restrict__ Bout,
                                              float* __restrict__ Fout, int N) {
    constexpr int FI = BM / 64;
    constexpr int FJ = BN / 64;
    constexpr int CPW = (BM + BN) / 32;  // stage instrs per wave per chunk (=8)
    constexpr int SZ = (BM + BN) * 64;   // one LDS buffer (ushorts, 32 KB)

    __shared__ ushort_t S[3 * SZ];       // 96 KB triple buffer

    const int t = threadIdx.x;
    const int lane = t & 63;
    const int w = t >> 6;
    const int wr = w >> 1;
    const int wc = w & 1;
    const int l31 = lane & 31;
    const int lh = lane >> 5;
    const int row0 = blockIdx.y * BM;
    const int col0 = blockIdx.x * BN;
    const int srow = lane >> 3;
    const int sk = (lane & 7) * 8;
    const int sw7 = l31 & 7;

    f32x16 acc[FI][FJ];
#pragma unroll
    for (int i = 0; i < FI; ++i)
#pragma unroll
        for (int j = 0; j < FJ; ++j)
#pragma unroll
            for (int r = 0; r < 16; ++r) acc[i][j][r] = 0.0f;

    // Per-chunk global source pointers for both phases (pre-swizzled global,
    // linear LDS dest; wave-uniform LDS base + lane*16).
    const ushort_t* gpA[CPW];
    const ushort_t* gpB[CPW];
    int lofs[CPW];
#pragma unroll
    for (int cc = 0; cc < CPW; ++cc) {
        int ch = cc * 4 + w;
        int r8 = ch * 8;
        lofs[cc] = ch * 512;
        if (r8 < BM) {
            gpA[cc] = A + (size_t)(row0 + r8 + srow) * K + sk;
            gpB[cc] = A2 ? (A2 + (size_t)(row0 + r8 + srow) * K2 + sk) : A;
        } else {
            gpA[cc] = BT + (size_t)(col0 + r8 - BM + srow) * K + sk;
            gpB[cc] = BT2 ? (BT2 + (size_t)(col0 + r8 - BM + srow) * K2 + sk) : BT;
        }
    }

    const int T1 = K >> 6;
    const int T2 = K2 >> 6;
    const int Ttot = T1 + T2;

    auto stage = [&](int tt, ushort_t* Sb) {
        if (tt < T1) {
#pragma unroll
            for (int cc = 0; cc < CPW; ++cc)
                async16(gpA[cc] + (size_t)tt * 64, &Sb[lofs[cc]]);
        } else {
            const int tl = tt - T1;
#pragma unroll
            for (int cc = 0; cc < CPW; ++cc)
                async16(gpB[cc] + (size_t)tl * 64, &Sb[lofs[cc]]);
        }
    };

    // prologue: chunks 0 and 1 in flight (2-deep)
    ushort_t* B0 = S;            // compute buffer (chunk tt)
    ushort_t* B1 = S + SZ;       // chunk tt+1 in flight
    ushort_t* B2 = S + 2 * SZ;   // chunk tt+2 stage target
    stage(0, B0);
    if (Ttot > 1) stage(1, B1);

    for (int tt = 0; tt < Ttot; ++tt) {
        // Counted wait: leave the NEXT chunk's CPW loads in flight; only the
        // oldest CPW (= chunk tt's stage) must have landed. Last chunk: drain.
        if (tt + 1 < Ttot) {
            asm volatile("s_waitcnt vmcnt(8)" ::: "memory");
        } else {
            asm volatile("s_waitcnt vmcnt(0)" ::: "memory");
        }
        __builtin_amdgcn_s_barrier();        // all waves certified chunk tt
        __builtin_amdgcn_sched_barrier(0);   // no hoisting across the barrier

        bf16x8 af[4][FI], bfm[4][FJ];
#pragma unroll
        for (int s = 0; s < 4; ++s) {
            int pos = ((2 * s + lh) ^ sw7) * 8;
#pragma unroll
            for (int i = 0; i < FI; ++i)
                af[s][i] = *(const bf16x8*)&B0[(wr * (BM / 2) + i * 32 + l31) * 64 + pos];
#pragma unroll
            for (int j = 0; j < FJ; ++j)
                bfm[s][j] = *(const bf16x8*)&B0[(BM + wc * (BN / 2) + j * 32 + l31) * 64 + pos];
        }
        // Issue chunk tt+2's stage into B2 = buffer last read at chunk tt-1;
        // all waves passed this chunk's barrier => those reads have landed.
        if (tt + 2 < Ttot) stage(tt + 2, B2);
#pragma unroll
        for (int s = 0; s < 4; ++s)
#pragma unroll
            for (int i = 0; i < FI; ++i)
#pragma unroll
                for (int j = 0; j < FJ; ++j)
                    acc[i][j] = __builtin_amdgcn_mfma_f32_32x32x16_bf16(af[s][i], bfm[s][j],
                                                                        acc[i][j], 0, 0, 0);
        ushort_t* tmp = B0; B0 = B1; B1 = B2; B2 = tmp;  // rotate
    }

    // epilogue: C/D layout col=lane&31, row=(reg&3)+8*(reg>>2)+4*(lane>>5)
#pragma unroll
    for (int i = 0; i < FI; ++i) {
#pragma unroll
        for (int j = 0; j < FJ; ++j) {
#pragma unroll
            for (int r = 0; r < 16; ++r) {
                int row = row0 + wr * (BM / 2) + i * 32 + (r & 3) + 8 * (r >> 2) + 4 * lh;
                int col = col0 + wc * (BN / 2) + j * 32 + l31;
                size_t off = (size_t)row * N + col;
                float v = acc[i][j][r];
                if (MODE == 1) {
                    Fout[off] = v;
                } else if (MODE == 2) {
                    float h = Xf[off];
                    float g = fminf(fmaxf(v - Rf[off], -1.0f), 1.0f);
                    float hn = h - ALPHA * g;
                    Hout[off] = hn;
                    Bout[swz64(row, col, N)] = f2bf(hn);
                } else if (MODE == 3) {
                    float h = Xf[off];
                    float g = fminf(fmaxf(v, -1.0f), 1.0f);
                    float hn = h - ALPHA * g;
                    Hout[off] = hn;
                    Bout[swz64(row, col, N)] = f2bf(hn);
                } else {  // MODE 4 (square M==N)
                    float vv = v + ((ADDI && row == col) ? 1.0f : 0.0f);
                    Bout[swz64(col, row, N)] = f2bf(vv);
                }
            }
        }
    }
}

extern "C" void kernel_launch(void* const* d_in, const int* in_sizes, int n_in,
                              void* d_out, int out_size, void* d_ws, size_t ws_size,
                              hipStream_t stream) {
    const float* X  = (const float*)d_in[0];  // [4096, 256, 8]
    const float* W1 = (const float*)d_in[1];  // [256, 128, 8]
    const float* W2 = (const float*)d_in[2];  // [128, 64, 8]
    const float* h1 = (const float*)d_in[3];  // [4096, 128, 8]
    const float* h2 = (const float*)d_in[4];  // [4096, 64, 8]
    float* out = (float*)d_out;

    const size_t szX  = (size_t)4096 * 2048;
    const size_t szH1 = (size_t)4096 * 1024;
    const size_t szH2 = (size_t)4096 * 512;

    float* outX = out;
    float* H1 = out + szX;
    float* H2 = H1 + szH1;

    // workspace (~77 MB of ~268 MB)
    ushort_t* M1fwdA  = (ushort_t*)d_ws;                 // [1024][2048]
    ushort_t* M1rbt   = M1fwdA + (size_t)1024 * 2048;    // [1024][2048]
    ushort_t* M2fwdA  = M1rbt + (size_t)1024 * 2048;     // [512][1024]
    ushort_t* M2rbt   = M2fwdA + (size_t)512 * 1024;     // [512][1024]
    ushort_t* M2rneg  = M2rbt + (size_t)512 * 1024;      // [512][1024]
    ushort_t* M2btneg = M2rneg + (size_t)512 * 1024;     // [1024][512]
    ushort_t* GmT1p   = M2btneg + (size_t)1024 * 512;    // [1024][1024]
    ushort_t* GmT2    = GmT1p + (size_t)1024 * 1024;     // [512][512]
    ushort_t* Xb      = GmT2 + (size_t)512 * 512;        // [4096][2048]
    ushort_t* H1bA    = Xb + szX;                        // [4096][1024]
    ushort_t* H1bB    = H1bA + szH1;
    ushort_t* H2bA    = H1bB + szH1;                     // [4096][512]
    ushort_t* H2bB    = H2bA + szH2;
    float*    R       = (float*)(H2bB + szH2);           // [4096][1024] fp32

    build_M_kernel<<<(256 * 128 * 64 + 255) / 256, 256, 0, stream>>>(
        W1, M1fwdA, M1rbt, nullptr, nullptr, 256, 128);
    build_M_kernel<<<(128 * 64 * 64 + 255) / 256, 256, 0, stream>>>(
        W2, M2fwdA, M2rbt, M2rneg, M2btneg, 128, 64);

    hipMemcpyAsync(H1, h1, szH1 * sizeof(float), hipMemcpyDeviceToDevice, stream);
    hipMemcpyAsync(H2, h2, szH2 * sizeof(float), hipMemcpyDeviceToDevice, stream);
    f2bf_swz_kernel<<<(int)((szX + 255) / 256), 256, 0, stream>>>(X, Xb, (int)szX, 11);
    f2bf_swz_kernel<<<(int)((szH1 + 255) / 256), 256, 0, stream>>>(h1, H1bA, (int)szH1, 10);
    f2bf_swz_kernel<<<(int)((szH2 + 255) / 256), 256, 0, stream>>>(h2, H2bA, (int)szH2, 9);

    // Precompute R = X@M1r (fp32), GmT1p = (M1@M1r + I)^T, GmT2 = (M2@M2r)^T
    gemm_k<1, 128, 128, false><<<dim3(8, 32), 256, 0, stream>>>(
        Xb, M1rbt, 2048, nullptr, nullptr, 0, nullptr, nullptr, nullptr, nullptr, R, 1024);
    gemm_k<4, 128, 128, true><<<dim3(8, 8), 256, 0, stream>>>(
        M1fwdA, M1rbt, 2048, nullptr, nullptr, 0, nullptr, nullptr, nullptr, GmT1p, nullptr, 1024);
    gemm_k<4, 128, 128, false><<<dim3(4, 4), 256, 0, stream>>>(
        M2fwdA, M2rbt, 1024, nullptr, nullptr, 0, nullptr, nullptr, nullptr, GmT2, nullptr, 512);

    ushort_t* H1old = H1bA; ushort_t* H1new = H1bB;
    ushort_t* H2old = H2bA; ushort_t* H2new = H2bB;
    for (int it = 0; it < N_ITER; ++it) {
        // A: H1 <- H1 - a*clip(H1@Gm1p - H2@M2 - R)   [4096x1024], K=1024+512
        gemm_k<2, 128, 128, false><<<dim3(8, 32), 256, 0, stream>>>(
            H1old, GmT1p, 1024, H2old, M2btneg, 512, H1, R, H1, H1new, nullptr, 1024);
        // B: H2 <- H2 - a*clip(H2@Gm2 - H1new@M2r)    [4096x512],  K=512+1024
        gemm_k<3, 128, 128, false><<<dim3(4, 32), 256, 0, stream>>>(
            H2old, GmT2, 512, H1new, M2rneg, 1024, H2, nullptr, H2, H2new, nullptr, 512);
        ushort_t* tmp;
        tmp = H1old; H1old = H1new; H1new = tmp;
        tmp = H2old; H2old = H2new; H2new = tmp;
    }

    // x passes through unchanged
    hipMemcpyAsync(outX, X, szX * sizeof(float), hipMemcpyDeviceToDevice, stream);
}

// Round 4
// 1119.285 us; speedup vs baseline: 1.2090x; 1.0949x over previous
//
#include <hip/hip_runtime.h>

#define N_ITER 20
#define ALPHA 0.01f

typedef unsigned short ushort_t;
typedef __attribute__((ext_vector_type(8))) short bf16x8;
typedef __attribute__((ext_vector_type(16))) float f32x16;

__device__ __forceinline__ float csign(int a, int b) {
    int s = 0;
    for (int aa = a >> 1; aa; aa >>= 1) s += __popc(aa & b);
    return (s & 1) ? -1.0f : 1.0f;
}

__device__ __forceinline__ float revsign(int b) {
    int k = __popc(b);
    return ((k * (k - 1) / 2) & 1) ? -1.0f : 1.0f;
}

__device__ __forceinline__ ushort_t f2bf(float f) {
    union { float f; unsigned u; } v;
    v.f = f;
    unsigned r = v.u + 0x7fffu + ((v.u >> 16) & 1u);  // RNE; inputs finite
    return (ushort_t)(r >> 16);
}

// Swizzled storage for logical (r, k) in an [R][K] bf16 operand buffer.
// Within each 64-elem k-group (128 B), 16B block j lives at j ^ (r&7).
// Verbatim LDS staging; fragment ds_read_b128 conflict-free (verified earlier).
__device__ __forceinline__ size_t swz64(int r, int k, int K) {
    return (size_t)r * K + (k & ~63) + ((((k >> 3) ^ r) & 7) << 3) + (k & 7);
}

__device__ __forceinline__ void async16(const void* g, void* l) {
    __builtin_amdgcn_global_load_lds((const __attribute__((address_space(1))) void*)g,
                                     (__attribute__((address_space(3))) void*)l, 16, 0, 0);
}

template <int N>
__device__ __forceinline__ void waitcnt_vm() {
    if constexpr (N == 0) asm volatile("s_waitcnt vmcnt(0)" ::: "memory");
    else if constexpr (N == 4) asm volatile("s_waitcnt vmcnt(4)" ::: "memory");
    else if constexpr (N == 6) asm volatile("s_waitcnt vmcnt(6)" ::: "memory");
    else if constexpr (N == 8) asm volatile("s_waitcnt vmcnt(8)" ::: "memory");
    else asm volatile("s_waitcnt vmcnt(0)" ::: "memory");
}

// Build bf16 swz64 GP matrices from W [P, Q, 8]:
//  MfA    [Q8][P8]: forward GP, A-layout    MfA[q8+a][p8+c]    = s*w
//  Mrbt   [Q8][P8]: reverse GP, B^T layout  Mrbt[q8+c][p8+a]   = s*rev*w
//  Mrneg  [Q8][P8]: -Mrbt
//  Mbtneg [P8][Q8]: -forward GP, B^T layout Mbtneg[p8+c][q8+a] = -s*w
__global__ void build_M_kernel(const float* __restrict__ W, ushort_t* __restrict__ MfA,
                               ushort_t* __restrict__ Mrbt, ushort_t* __restrict__ Mrneg,
                               ushort_t* __restrict__ Mbtneg, int P, int Q) {
    int idx = blockIdx.x * blockDim.x + threadIdx.x;
    int total = P * Q * 64;
    if (idx >= total) return;
    int c = idx & 7;
    int a = (idx >> 3) & 7;
    int pq = idx >> 6;
    int q = pq % Q;
    int p = pq / Q;
    int b = a ^ c;
    float w = W[((size_t)p * Q + q) * 8 + b];
    float fw = csign(a, b) * w;
    float rw = csign(a, b) * revsign(b) * w;
    MfA[swz64(q * 8 + a, p * 8 + c, P * 8)] = f2bf(fw);
    Mrbt[swz64(q * 8 + c, p * 8 + a, P * 8)] = f2bf(rw);
    if (Mrneg) Mrneg[swz64(q * 8 + c, p * 8 + a, P * 8)] = f2bf(-rw);
    if (Mbtneg) Mbtneg[swz64(p * 8 + c, q * 8 + a, Q * 8)] = f2bf(-fw);
}

// fp32 [R][K] plain -> bf16 swz64
__global__ void f2bf_swz_kernel(const float* __restrict__ in, ushort_t* __restrict__ out,
                                int n, int kshift) {
    int i = blockIdx.x * blockDim.x + threadIdx.x;
    if (i >= n) return;
    int K = 1 << kshift;
    int r = i >> kshift;
    int k = i & (K - 1);
    out[swz64(r, k, K)] = f2bf(in[i]);
}

// MFMA bf16 GEMM. BMxBN block, BK=64, 256 threads (4 waves 2x2), wave tile
// (BM/2)x(BN/2) of 32x32x16 MFMAs. TRIPLE-buffered LDS, 2-chunk-ahead prefetch
// via global_load_lds, counted s_waitcnt vmcnt(CPW) (never drained to 0 in the
// main loop), one raw s_barrier per chunk, stage issued immediately after the
// barrier (before ds_reads) for max load-latency overlap. Tile sized so >=2
// blocks/CU co-reside (LDS 3*(BM+BN)*128B must be <= 80 KB for 2/CU).
// Two accumulation phases (K then K2) unified into one chunk sequence.
// MODE 1: Fout fp32 = acc                                       (R precompute)
// MODE 2: g=clip(acc - Rf); hn=Xf - a*g; Hout=hn fp32; Bout=swz64(hn)   (H1 update)
// MODE 3: g=clip(acc);      hn=Xf - a*g; Hout=hn fp32; Bout=swz64(hn)   (H2 update)
// MODE 4: Bout[swz64(col,row,N)] = bf16(acc + (ADDI && row==col))       (GmT build)
template <int MODE, int BM, int BN, bool ADDI>
__global__ __launch_bounds__(256) void gemm_k(const ushort_t* __restrict__ A,
                                              const ushort_t* __restrict__ BT, int K,
                                              const ushort_t* __restrict__ A2,
                                              const ushort_t* __restrict__ BT2, int K2,
                                              const float* __restrict__ Xf,
                                              const float* __restrict__ Rf,
                                              float* __restrict__ Hout,
                                              ushort_t* __restrict__ Bout,
                                              float* __restrict__ Fout, int N) {
    constexpr int FI = BM / 64;
    constexpr int FJ = BN / 64;
    constexpr int CPW = (BM + BN) / 32;  // stage instrs per wave per chunk
    constexpr int SZ = (BM + BN) * 64;   // one LDS buffer (ushorts)

    __shared__ ushort_t S[3 * SZ];       // triple buffer

    const int t = threadIdx.x;
    const int lane = t & 63;
    const int w = t >> 6;
    const int wr = w >> 1;
    const int wc = w & 1;
    const int l31 = lane & 31;
    const int lh = lane >> 5;
    const int row0 = blockIdx.y * BM;
    const int col0 = blockIdx.x * BN;
    const int srow = lane >> 3;
    const int sk = (lane & 7) * 8;
    const int sw7 = l31 & 7;

    f32x16 acc[FI][FJ];
#pragma unroll
    for (int i = 0; i < FI; ++i)
#pragma unroll
        for (int j = 0; j < FJ; ++j)
#pragma unroll
            for (int r = 0; r < 16; ++r) acc[i][j][r] = 0.0f;

    // Per-chunk global source pointers for both phases (pre-swizzled global,
    // linear LDS dest; wave-uniform LDS base + lane*16).
    const ushort_t* gpA[CPW];
    const ushort_t* gpB[CPW];
    int lofs[CPW];
#pragma unroll
    for (int cc = 0; cc < CPW; ++cc) {
        int ch = cc * 4 + w;
        int r8 = ch * 8;
        lofs[cc] = ch * 512;
        if (r8 < BM) {
            gpA[cc] = A + (size_t)(row0 + r8 + srow) * K + sk;
            gpB[cc] = A2 ? (A2 + (size_t)(row0 + r8 + srow) * K2 + sk) : A;
        } else {
            gpA[cc] = BT + (size_t)(col0 + r8 - BM + srow) * K + sk;
            gpB[cc] = BT2 ? (BT2 + (size_t)(col0 + r8 - BM + srow) * K2 + sk) : BT;
        }
    }

    const int T1 = K >> 6;
    const int T2 = K2 >> 6;
    const int Ttot = T1 + T2;

    auto stage = [&](int tt, ushort_t* Sb) {
        if (tt < T1) {
#pragma unroll
            for (int cc = 0; cc < CPW; ++cc)
                async16(gpA[cc] + (size_t)tt * 64, &Sb[lofs[cc]]);
        } else {
            const int tl = tt - T1;
#pragma unroll
            for (int cc = 0; cc < CPW; ++cc)
                async16(gpB[cc] + (size_t)tl * 64, &Sb[lofs[cc]]);
        }
    };

    // prologue: chunks 0 and 1 in flight (2-deep)
    ushort_t* B0 = S;            // compute buffer (chunk tt)
    ushort_t* B1 = S + SZ;       // chunk tt+1 in flight
    ushort_t* B2 = S + 2 * SZ;   // chunk tt+2 stage target
    stage(0, B0);
    if (Ttot > 1) stage(1, B1);

    for (int tt = 0; tt < Ttot; ++tt) {
        // Counted wait: certify chunk tt's CPW loads landed (each wave's own);
        // leave chunk tt+1's CPW in flight. Barrier then makes it collective.
        if (tt + 1 < Ttot) {
            waitcnt_vm<CPW>();
        } else {
            waitcnt_vm<0>();
        }
        __builtin_amdgcn_s_barrier();        // all waves certified chunk tt
        __builtin_amdgcn_sched_barrier(0);   // no hoisting across the barrier

        // Issue chunk tt+2's stage FIRST: B2 was last read at chunk tt-1, and
        // this barrier certified those reads. Loads get ~1.5 chunks to land.
        if (tt + 2 < Ttot) stage(tt + 2, B2);

        bf16x8 af[4][FI], bfm[4][FJ];
#pragma unroll
        for (int s = 0; s < 4; ++s) {
            int pos = ((2 * s + lh) ^ sw7) * 8;
#pragma unroll
            for (int i = 0; i < FI; ++i)
                af[s][i] = *(const bf16x8*)&B0[(wr * (BM / 2) + i * 32 + l31) * 64 + pos];
#pragma unroll
            for (int j = 0; j < FJ; ++j)
                bfm[s][j] = *(const bf16x8*)&B0[(BM + wc * (BN / 2) + j * 32 + l31) * 64 + pos];
        }
#pragma unroll
        for (int s = 0; s < 4; ++s)
#pragma unroll
            for (int i = 0; i < FI; ++i)
#pragma unroll
                for (int j = 0; j < FJ; ++j)
                    acc[i][j] = __builtin_amdgcn_mfma_f32_32x32x16_bf16(af[s][i], bfm[s][j],
                                                                        acc[i][j], 0, 0, 0);
        ushort_t* tmp = B0; B0 = B1; B1 = B2; B2 = tmp;  // rotate
    }

    // epilogue: C/D layout col=lane&31, row=(reg&3)+8*(reg>>2)+4*(lane>>5)
#pragma unroll
    for (int i = 0; i < FI; ++i) {
#pragma unroll
        for (int j = 0; j < FJ; ++j) {
#pragma unroll
            for (int r = 0; r < 16; ++r) {
                int row = row0 + wr * (BM / 2) + i * 32 + (r & 3) + 8 * (r >> 2) + 4 * lh;
                int col = col0 + wc * (BN / 2) + j * 32 + l31;
                size_t off = (size_t)row * N + col;
                float v = acc[i][j][r];
                if (MODE == 1) {
                    Fout[off] = v;
                } else if (MODE == 2) {
                    float h = Xf[off];
                    float g = fminf(fmaxf(v - Rf[off], -1.0f), 1.0f);
                    float hn = h - ALPHA * g;
                    Hout[off] = hn;
                    Bout[swz64(row, col, N)] = f2bf(hn);
                } else if (MODE == 3) {
                    float h = Xf[off];
                    float g = fminf(fmaxf(v, -1.0f), 1.0f);
                    float hn = h - ALPHA * g;
                    Hout[off] = hn;
                    Bout[swz64(row, col, N)] = f2bf(hn);
                } else {  // MODE 4 (square matrix output)
                    float vv = v + ((ADDI && row == col) ? 1.0f : 0.0f);
                    Bout[swz64(col, row, N)] = f2bf(vv);
                }
            }
        }
    }
}

extern "C" void kernel_launch(void* const* d_in, const int* in_sizes, int n_in,
                              void* d_out, int out_size, void* d_ws, size_t ws_size,
                              hipStream_t stream) {
    const float* X  = (const float*)d_in[0];  // [4096, 256, 8]
    const float* W1 = (const float*)d_in[1];  // [256, 128, 8]
    const float* W2 = (const float*)d_in[2];  // [128, 64, 8]
    const float* h1 = (const float*)d_in[3];  // [4096, 128, 8]
    const float* h2 = (const float*)d_in[4];  // [4096, 64, 8]
    float* out = (float*)d_out;

    const size_t szX  = (size_t)4096 * 2048;
    const size_t szH1 = (size_t)4096 * 1024;
    const size_t szH2 = (size_t)4096 * 512;

    float* outX = out;
    float* H1 = out + szX;
    float* H2 = H1 + szH1;

    // workspace (~77 MB of ~268 MB)
    ushort_t* M1fwdA  = (ushort_t*)d_ws;                 // [1024][2048]
    ushort_t* M1rbt   = M1fwdA + (size_t)1024 * 2048;    // [1024][2048]
    ushort_t* M2fwdA  = M1rbt + (size_t)1024 * 2048;     // [512][1024]
    ushort_t* M2rbt   = M2fwdA + (size_t)512 * 1024;     // [512][1024]
    ushort_t* M2rneg  = M2rbt + (size_t)512 * 1024;      // [512][1024]
    ushort_t* M2btneg = M2rneg + (size_t)512 * 1024;     // [1024][512]
    ushort_t* GmT1p   = M2btneg + (size_t)1024 * 512;    // [1024][1024]
    ushort_t* GmT2    = GmT1p + (size_t)1024 * 1024;     // [512][512]
    ushort_t* Xb      = GmT2 + (size_t)512 * 512;        // [4096][2048]
    ushort_t* H1bA    = Xb + szX;                        // [4096][1024]
    ushort_t* H1bB    = H1bA + szH1;
    ushort_t* H2bA    = H1bB + szH1;                     // [4096][512]
    ushort_t* H2bB    = H2bA + szH2;
    float*    R       = (float*)(H2bB + szH2);           // [4096][1024] fp32

    build_M_kernel<<<(256 * 128 * 64 + 255) / 256, 256, 0, stream>>>(
        W1, M1fwdA, M1rbt, nullptr, nullptr, 256, 128);
    build_M_kernel<<<(128 * 64 * 64 + 255) / 256, 256, 0, stream>>>(
        W2, M2fwdA, M2rbt, M2rneg, M2btneg, 128, 64);

    hipMemcpyAsync(H1, h1, szH1 * sizeof(float), hipMemcpyDeviceToDevice, stream);
    hipMemcpyAsync(H2, h2, szH2 * sizeof(float), hipMemcpyDeviceToDevice, stream);
    f2bf_swz_kernel<<<(int)((szX + 255) / 256), 256, 0, stream>>>(X, Xb, (int)szX, 11);
    f2bf_swz_kernel<<<(int)((szH1 + 255) / 256), 256, 0, stream>>>(h1, H1bA, (int)szH1, 10);
    f2bf_swz_kernel<<<(int)((szH2 + 255) / 256), 256, 0, stream>>>(h2, H2bA, (int)szH2, 9);

    // Precompute R = X@M1r (fp32), GmT1p = (M1@M1r + I)^T, GmT2 = (M2@M2r)^T
    gemm_k<1, 128, 64, false><<<dim3(16, 32), 256, 0, stream>>>(
        Xb, M1rbt, 2048, nullptr, nullptr, 0, nullptr, nullptr, nullptr, nullptr, R, 1024);
    gemm_k<4, 128, 64, true><<<dim3(16, 8), 256, 0, stream>>>(
        M1fwdA, M1rbt, 2048, nullptr, nullptr, 0, nullptr, nullptr, nullptr, GmT1p, nullptr, 1024);
    gemm_k<4, 64, 64, false><<<dim3(8, 8), 256, 0, stream>>>(
        M2fwdA, M2rbt, 1024, nullptr, nullptr, 0, nullptr, nullptr, nullptr, GmT2, nullptr, 512);

    ushort_t* H1old = H1bA; ushort_t* H1new = H1bB;
    ushort_t* H2old = H2bA; ushort_t* H2new = H2bB;
    for (int it = 0; it < N_ITER; ++it) {
        // A: H1 <- H1 - a*clip(H1@Gm1p - H2@M2 - R)   [4096x1024], K=1024+512
        gemm_k<2, 128, 64, false><<<dim3(16, 32), 256, 0, stream>>>(
            H1old, GmT1p, 1024, H2old, M2btneg, 512, H1, R, H1, H1new, nullptr, 1024);
        // B: H2 <- H2 - a*clip(H2@Gm2 - H1new@M2r)    [4096x512],  K=512+1024
        gemm_k<3, 64, 64, false><<<dim3(8, 64), 256, 0, stream>>>(
            H2old, GmT2, 512, H1new, M2rneg, 1024, H2, nullptr, H2, H2new, nullptr, 512);
        ushort_t* tmp;
        tmp = H1old; H1old = H1new; H1new = tmp;
        tmp = H2old; H2old = H2new; H2new = tmp;
    }

    // x passes through unchanged
    hipMemcpyAsync(outX, X, szX * sizeof(float), hipMemcpyDeviceToDevice, stream);
}

// Round 6
// 1015.183 us; speedup vs baseline: 1.3330x; 1.1025x over previous
//
#include <hip/hip_runtime.h>

#define N_ITER 20
#define ALPHA 0.01f

typedef unsigned short ushort_t;
typedef __attribute__((ext_vector_type(8))) short bf16x8;
typedef __attribute__((ext_vector_type(16))) float f32x16;

__device__ __forceinline__ float csign(int a, int b) {
    int s = 0;
    for (int aa = a >> 1; aa; aa >>= 1) s += __popc(aa & b);
    return (s & 1) ? -1.0f : 1.0f;
}

__device__ __forceinline__ float revsign(int b) {
    int k = __popc(b);
    return ((k * (k - 1) / 2) & 1) ? -1.0f : 1.0f;
}

__device__ __forceinline__ ushort_t f2bf(float f) {
    union { float f; unsigned u; } v;
    v.f = f;
    unsigned r = v.u + 0x7fffu + ((v.u >> 16) & 1u);  // RNE; inputs finite
    return (ushort_t)(r >> 16);
}

// Swizzled storage for logical (r, k) in an [R][K] bf16 operand buffer.
// Within each 64-elem k-group (128 B), 16B block j lives at j ^ (r&7).
// Verbatim LDS staging; fragment ds_read_b128 conflict-free (verified earlier).
__device__ __forceinline__ size_t swz64(int r, int k, int K) {
    return (size_t)r * K + (k & ~63) + ((((k >> 3) ^ r) & 7) << 3) + (k & 7);
}

__device__ __forceinline__ void async16(const void* g, void* l) {
    __builtin_amdgcn_global_load_lds((const __attribute__((address_space(1))) void*)g,
                                     (__attribute__((address_space(3))) void*)l, 16, 0, 0);
}

template <int N>
__device__ __forceinline__ void waitcnt_vm() {
    if constexpr (N == 0) asm volatile("s_waitcnt vmcnt(0)" ::: "memory");
    else if constexpr (N == 4) asm volatile("s_waitcnt vmcnt(4)" ::: "memory");
    else if constexpr (N == 6) asm volatile("s_waitcnt vmcnt(6)" ::: "memory");
    else if constexpr (N == 8) asm volatile("s_waitcnt vmcnt(8)" ::: "memory");
    else asm volatile("s_waitcnt vmcnt(0)" ::: "memory");
}

// Build bf16 swz64 GP matrices from W [P, Q, 8]:
//  MfA    [Q8][P8]: forward GP, A-layout    MfA[q8+a][p8+c]    = s*w
//  Mrbt   [Q8][P8]: reverse GP, B^T layout  Mrbt[q8+c][p8+a]   = s*rev*w
//  Mrneg  [Q8][P8]: -Mrbt
//  Mbtneg [P8][Q8]: -forward GP, B^T layout Mbtneg[p8+c][q8+a] = -s*w
__global__ void build_M_kernel(const float* __restrict__ W, ushort_t* __restrict__ MfA,
                               ushort_t* __restrict__ Mrbt, ushort_t* __restrict__ Mrneg,
                               ushort_t* __restrict__ Mbtneg, int P, int Q) {
    int idx = blockIdx.x * blockDim.x + threadIdx.x;
    int total = P * Q * 64;
    if (idx >= total) return;
    int c = idx & 7;
    int a = (idx >> 3) & 7;
    int pq = idx >> 6;
    int q = pq % Q;
    int p = pq / Q;
    int b = a ^ c;
    float w = W[((size_t)p * Q + q) * 8 + b];
    float fw = csign(a, b) * w;
    float rw = csign(a, b) * revsign(b) * w;
    MfA[swz64(q * 8 + a, p * 8 + c, P * 8)] = f2bf(fw);
    Mrbt[swz64(q * 8 + c, p * 8 + a, P * 8)] = f2bf(rw);
    if (Mrneg) Mrneg[swz64(q * 8 + c, p * 8 + a, P * 8)] = f2bf(-rw);
    if (Mbtneg) Mbtneg[swz64(p * 8 + c, q * 8 + a, Q * 8)] = f2bf(-fw);
}

// fp32 [R][K] plain -> bf16 swz64
__global__ void f2bf_swz_kernel(const float* __restrict__ in, ushort_t* __restrict__ out,
                                int n, int kshift) {
    int i = blockIdx.x * blockDim.x + threadIdx.x;
    if (i >= n) return;
    int K = 1 << kshift;
    int r = i >> kshift;
    int k = i & (K - 1);
    out[swz64(r, k, K)] = f2bf(in[i]);
}

// MFMA bf16 GEMM. BMxBN block, BK=64, 256 threads (4 waves 2x2), wave tile
// (BM/2)x(BN/2) of 32x32x16 MFMAs. TRIPLE-buffered LDS, 2-chunk-ahead prefetch
// via global_load_lds, counted s_waitcnt vmcnt(CPW) (never drained to 0 in the
// main loop), one raw s_barrier per chunk, stage issued immediately after the
// barrier. (Round-4 verified core.)
//
// XCD-aware swizzle (T1): launched with a 1-D grid of GX*GY blocks, GY % 8 == 0,
// ypx = GY/8. Consecutive workgroup IDs round-robin across the 8 XCDs, so:
//   xcd = wg & 7; idx = wg >> 3; by = xcd*ypx + idx % ypx; bx = idx / ypx;
// gives XCD k the row-tile group [k*ypx, (k+1)*ypx) for ALL column tiles:
// A-operand row-slices stay resident in that XCD's L2 (read by all bx), and
// within an XCD the ypx row-tiles of one weight column-block run adjacently.
// Bijective: (xcd, idx%ypx, idx/ypx) <-> (by, bx).
//
// MODE 1: Fout fp32 = acc                                       (R precompute)
// MODE 2: g=clip(acc - Rf); hn=Xf - a*g; Hout=hn fp32; Bout=swz64(hn)   (H1 update)
// MODE 3: g=clip(acc);      hn=Xf - a*g; Hout=hn fp32; Bout=swz64(hn)   (H2 update)
// MODE 4: Bout[swz64(col,row,N)] = bf16(acc + (ADDI && row==col))       (GmT build)
template <int MODE, int BM, int BN, bool ADDI>
__global__ __launch_bounds__(256) void gemm_k(const ushort_t* __restrict__ A,
                                              const ushort_t* __restrict__ BT, int K,
                                              const ushort_t* __restrict__ A2,
                                              const ushort_t* __restrict__ BT2, int K2,
                                              const float* __restrict__ Xf,
                                              const float* __restrict__ Rf,
                                              float* __restrict__ Hout,
                                              ushort_t* __restrict__ Bout,
                                              float* __restrict__ Fout, int N, int ypx) {
    constexpr int FI = BM / 64;
    constexpr int FJ = BN / 64;
    constexpr int CPW = (BM + BN) / 32;  // stage instrs per wave per chunk
    constexpr int SZ = (BM + BN) * 64;   // one LDS buffer (ushorts)

    __shared__ ushort_t S[3 * SZ];       // triple buffer

    const int wg = blockIdx.x;
    const int xcd = wg & 7;
    const int idx = wg >> 3;
    const int by = xcd * ypx + idx % ypx;
    const int bx = idx / ypx;

    const int t = threadIdx.x;
    const int lane = t & 63;
    const int w = t >> 6;
    const int wr = w >> 1;
    const int wc = w & 1;
    const int l31 = lane & 31;
    const int lh = lane >> 5;
    const int row0 = by * BM;
    const int col0 = bx * BN;
    const int srow = lane >> 3;
    const int sk = (lane & 7) * 8;
    const int sw7 = l31 & 7;

    f32x16 acc[FI][FJ];
#pragma unroll
    for (int i = 0; i < FI; ++i)
#pragma unroll
        for (int j = 0; j < FJ; ++j)
#pragma unroll
            for (int r = 0; r < 16; ++r) acc[i][j][r] = 0.0f;

    // Per-chunk global source pointers for both phases (pre-swizzled global,
    // linear LDS dest; wave-uniform LDS base + lane*16).
    const ushort_t* gpA[CPW];
    const ushort_t* gpB[CPW];
    int lofs[CPW];
#pragma unroll
    for (int cc = 0; cc < CPW; ++cc) {
        int ch = cc * 4 + w;
        int r8 = ch * 8;
        lofs[cc] = ch * 512;
        if (r8 < BM) {
            gpA[cc] = A + (size_t)(row0 + r8 + srow) * K + sk;
            gpB[cc] = A2 ? (A2 + (size_t)(row0 + r8 + srow) * K2 + sk) : A;
        } else {
            gpA[cc] = BT + (size_t)(col0 + r8 - BM + srow) * K + sk;
            gpB[cc] = BT2 ? (BT2 + (size_t)(col0 + r8 - BM + srow) * K2 + sk) : BT;
        }
    }

    const int T1 = K >> 6;
    const int T2 = K2 >> 6;
    const int Ttot = T1 + T2;

    auto stage = [&](int tt, ushort_t* Sb) {
        if (tt < T1) {
#pragma unroll
            for (int cc = 0; cc < CPW; ++cc)
                async16(gpA[cc] + (size_t)tt * 64, &Sb[lofs[cc]]);
        } else {
            const int tl = tt - T1;
#pragma unroll
            for (int cc = 0; cc < CPW; ++cc)
                async16(gpB[cc] + (size_t)tl * 64, &Sb[lofs[cc]]);
        }
    };

    // prologue: chunks 0 and 1 in flight (2-deep)
    ushort_t* B0 = S;            // compute buffer (chunk tt)
    ushort_t* B1 = S + SZ;       // chunk tt+1 in flight
    ushort_t* B2 = S + 2 * SZ;   // chunk tt+2 stage target
    stage(0, B0);
    if (Ttot > 1) stage(1, B1);

    for (int tt = 0; tt < Ttot; ++tt) {
        // Counted wait: certify chunk tt's CPW loads landed (each wave's own);
        // leave chunk tt+1's CPW in flight. Barrier then makes it collective.
        if (tt + 1 < Ttot) {
            waitcnt_vm<CPW>();
        } else {
            waitcnt_vm<0>();
        }
        __builtin_amdgcn_s_barrier();        // all waves certified chunk tt
        __builtin_amdgcn_sched_barrier(0);   // no hoisting across the barrier

        // Issue chunk tt+2's stage FIRST: B2 was last read at chunk tt-1, and
        // this barrier certified those reads. Loads get ~1.5 chunks to land.
        if (tt + 2 < Ttot) stage(tt + 2, B2);

        bf16x8 af[4][FI], bfm[4][FJ];
#pragma unroll
        for (int s = 0; s < 4; ++s) {
            int pos = ((2 * s + lh) ^ sw7) * 8;
#pragma unroll
            for (int i = 0; i < FI; ++i)
                af[s][i] = *(const bf16x8*)&B0[(wr * (BM / 2) + i * 32 + l31) * 64 + pos];
#pragma unroll
            for (int j = 0; j < FJ; ++j)
                bfm[s][j] = *(const bf16x8*)&B0[(BM + wc * (BN / 2) + j * 32 + l31) * 64 + pos];
        }
#pragma unroll
        for (int s = 0; s < 4; ++s)
#pragma unroll
            for (int i = 0; i < FI; ++i)
#pragma unroll
                for (int j = 0; j < FJ; ++j)
                    acc[i][j] = __builtin_amdgcn_mfma_f32_32x32x16_bf16(af[s][i], bfm[s][j],
                                                                        acc[i][j], 0, 0, 0);
        ushort_t* tmp = B0; B0 = B1; B1 = B2; B2 = tmp;  // rotate
    }

    // epilogue: C/D layout col=lane&31, row=(reg&3)+8*(reg>>2)+4*(lane>>5)
#pragma unroll
    for (int i = 0; i < FI; ++i) {
#pragma unroll
        for (int j = 0; j < FJ; ++j) {
#pragma unroll
            for (int r = 0; r < 16; ++r) {
                int row = row0 + wr * (BM / 2) + i * 32 + (r & 3) + 8 * (r >> 2) + 4 * lh;
                int col = col0 + wc * (BN / 2) + j * 32 + l31;
                size_t off = (size_t)row * N + col;
                float v = acc[i][j][r];
                if (MODE == 1) {
                    Fout[off] = v;
                } else if (MODE == 2) {
                    float h = Xf[off];
                    float g = fminf(fmaxf(v - Rf[off], -1.0f), 1.0f);
                    float hn = h - ALPHA * g;
                    Hout[off] = hn;
                    Bout[swz64(row, col, N)] = f2bf(hn);
                } else if (MODE == 3) {
                    float h = Xf[off];
                    float g = fminf(fmaxf(v, -1.0f), 1.0f);
                    float hn = h - ALPHA * g;
                    Hout[off] = hn;
                    Bout[swz64(row, col, N)] = f2bf(hn);
                } else {  // MODE 4 (square matrix output)
                    float vv = v + ((ADDI && row == col) ? 1.0f : 0.0f);
                    Bout[swz64(col, row, N)] = f2bf(vv);
                }
            }
        }
    }
}

extern "C" void kernel_launch(void* const* d_in, const int* in_sizes, int n_in,
                              void* d_out, int out_size, void* d_ws, size_t ws_size,
                              hipStream_t stream) {
    const float* X  = (const float*)d_in[0];  // [4096, 256, 8]
    const float* W1 = (const float*)d_in[1];  // [256, 128, 8]
    const float* W2 = (const float*)d_in[2];  // [128, 64, 8]
    const float* h1 = (const float*)d_in[3];  // [4096, 128, 8]
    const float* h2 = (const float*)d_in[4];  // [4096, 64, 8]
    float* out = (float*)d_out;

    const size_t szX  = (size_t)4096 * 2048;
    const size_t szH1 = (size_t)4096 * 1024;
    const size_t szH2 = (size_t)4096 * 512;

    float* outX = out;
    float* H1 = out + szX;
    float* H2 = H1 + szH1;

    // workspace (~77 MB of ~268 MB)
    ushort_t* M1fwdA  = (ushort_t*)d_ws;                 // [1024][2048]
    ushort_t* M1rbt   = M1fwdA + (size_t)1024 * 2048;    // [1024][2048]
    ushort_t* M2fwdA  = M1rbt + (size_t)1024 * 2048;     // [512][1024]
    ushort_t* M2rbt   = M2fwdA + (size_t)512 * 1024;     // [512][1024]
    ushort_t* M2rneg  = M2rbt + (size_t)512 * 1024;      // [512][1024]
    ushort_t* M2btneg = M2rneg + (size_t)512 * 1024;     // [1024][512]
    ushort_t* GmT1p   = M2btneg + (size_t)1024 * 512;    // [1024][1024]
    ushort_t* GmT2    = GmT1p + (size_t)1024 * 1024;     // [512][512]
    ushort_t* Xb      = GmT2 + (size_t)512 * 512;        // [4096][2048]
    ushort_t* H1bA    = Xb + szX;                        // [4096][1024]
    ushort_t* H1bB    = H1bA + szH1;
    ushort_t* H2bA    = H1bB + szH1;                     // [4096][512]
    ushort_t* H2bB    = H2bA + szH2;
    float*    R       = (float*)(H2bB + szH2);           // [4096][1024] fp32

    build_M_kernel<<<(256 * 128 * 64 + 255) / 256, 256, 0, stream>>>(
        W1, M1fwdA, M1rbt, nullptr, nullptr, 256, 128);
    build_M_kernel<<<(128 * 64 * 64 + 255) / 256, 256, 0, stream>>>(
        W2, M2fwdA, M2rbt, M2rneg, M2btneg, 128, 64);

    hipMemcpyAsync(H1, h1, szH1 * sizeof(float), hipMemcpyDeviceToDevice, stream);
    hipMemcpyAsync(H2, h2, szH2 * sizeof(float), hipMemcpyDeviceToDevice, stream);
    f2bf_swz_kernel<<<(int)((szX + 255) / 256), 256, 0, stream>>>(X, Xb, (int)szX, 11);
    f2bf_swz_kernel<<<(int)((szH1 + 255) / 256), 256, 0, stream>>>(h1, H1bA, (int)szH1, 10);
    f2bf_swz_kernel<<<(int)((szH2 + 255) / 256), 256, 0, stream>>>(h2, H2bA, (int)szH2, 9);

    // Precompute R = X@M1r (fp32), GmT1p = (M1@M1r + I)^T, GmT2 = (M2@M2r)^T
    // (1-D grids; gemm_k decodes (bx,by) with XCD swizzle, ypx = GY/8)
    gemm_k<1, 128, 64, false><<<dim3(16 * 32), 256, 0, stream>>>(
        Xb, M1rbt, 2048, nullptr, nullptr, 0, nullptr, nullptr, nullptr, nullptr, R, 1024, 4);
    gemm_k<4, 128, 64, true><<<dim3(16 * 8), 256, 0, stream>>>(
        M1fwdA, M1rbt, 2048, nullptr, nullptr, 0, nullptr, nullptr, nullptr, GmT1p, nullptr, 1024, 1);
    gemm_k<4, 64, 64, false><<<dim3(8 * 8), 256, 0, stream>>>(
        M2fwdA, M2rbt, 1024, nullptr, nullptr, 0, nullptr, nullptr, nullptr, GmT2, nullptr, 512, 1);

    ushort_t* H1old = H1bA; ushort_t* H1new = H1bB;
    ushort_t* H2old = H2bA; ushort_t* H2new = H2bB;
    for (int it = 0; it < N_ITER; ++it) {
        // A: H1 <- H1 - a*clip(H1@Gm1p - H2@M2 - R)   [4096x1024], K=1024+512
        gemm_k<2, 128, 64, false><<<dim3(16 * 32), 256, 0, stream>>>(
            H1old, GmT1p, 1024, H2old, M2btneg, 512, H1, R, H1, H1new, nullptr, 1024, 4);
        // B: H2 <- H2 - a*clip(H2@Gm2 - H1new@M2r)    [4096x512],  K=512+1024
        gemm_k<3, 64, 64, false><<<dim3(8 * 64), 256, 0, stream>>>(
            H2old, GmT2, 512, H1new, M2rneg, 1024, H2, nullptr, H2, H2new, nullptr, 512, 8);
        ushort_t* tmp;
        tmp = H1old; H1old = H1new; H1new = tmp;
        tmp = H2old; H2old = H2new; H2new = tmp;
    }

    // x passes through unchanged
    hipMemcpyAsync(outX, X, szX * sizeof(float), hipMemcpyDeviceToDevice, stream);
}